// Round 11
// baseline (241.844 us; speedup 1.0000x reference)
//
#include <hip/hip_runtime.h>
#include <hip/hip_bf16.h>
#include <math.h>

// Causal attention fwd: B=1,H=16,S=4096,D=64 fp32 in/out.
// 32x32x16-MFMA flash kernel, swapped QK^T (S^T = K*Q), in-register softmax,
// defer-max (THR=8, exp2 domain), KB=64 double-buffered LDS (32KB), one
// barrier/iter, launch_bounds(256,3) (no spill). Round 10 (resubmit + guard):
//  - per-XCD work queues via s_getreg(HW_REG_XCC_ID): head h -> XCD h&7,
//    so each XCD's 4MB L2 keeps its 2 heads' K/V resident
//  - item order: chunk-index OUTER, j desc inner -> all blocks of an XCD
//    stream the SAME k-range concurrently (hot set <= 4MB = L2)
//  - ws-adaptive chunk length Lt in {8,16,22,32}; monolithic fallback
//  - NEW guard: after own queue drains, sweep the other queues (correctness
//    no longer depends on XCC_ID distribution; G16)

typedef __bf16 bf16;
typedef __bf16 bf16x8 __attribute__((ext_vector_type(8)));
typedef float f32x16 __attribute__((ext_vector_type(16)));

#define NH 16
#define SEQ 4096
#define DH 64
#define QB 128
#define WQ 32
#define KB 64
#define NJ 32
#define LOG2E 1.44269504088896340736f

static __device__ __forceinline__ void mfma32(f32x16& c, bf16x8 a, bf16x8 b) {
  asm("v_mfma_f32_32x32x16_bf16 %0, %1, %2, %0" : "+v"(c) : "v"(a), "v"(b));
}
static __device__ __forceinline__ float exp2a(float x) {
  float r; asm("v_exp_f32 %0, %1" : "=v"(r) : "v"(x)); return r;
}
static __device__ __forceinline__ unsigned pk(float lo, float hi) {
  unsigned r; asm("v_cvt_pk_bf16_f32 %0, %1, %2" : "=v"(r) : "v"(lo), "v"(hi)); return r;
}
static __device__ __forceinline__ void swap32(unsigned& a, unsigned& b) {
  asm("v_permlane32_swap_b32 %0, %1" : "+v"(a), "+v"(b));
}

union AFrag { unsigned u[4]; bf16x8 v; };

static __device__ __forceinline__ bf16x8 cvt8(float4 a, float4 b) {
  bf16x8 f;
  f[0]=(bf16)a.x; f[1]=(bf16)a.y; f[2]=(bf16)a.z; f[3]=(bf16)a.w;
  f[4]=(bf16)b.x; f[5]=(bf16)b.y; f[6]=(bf16)b.z; f[7]=(bf16)b.w;
  return f;
}

__global__ void zero_ctr(unsigned* c) {
  if (threadIdx.x < 8) c[threadIdx.x * 16] = 0;   // 8 queues, 64B apart
}

// ws layout: 8 counters @0 (64B apart, 512B); wsO @1024 (nslot*16384 B bf16);
// wsM @1024+nslot*16384 (nslot*512 B f32); wsL after (nslot*512 B f32).
// slot = (sbase_j + ci)*16 + head, sbase_j = sum ncj over jj>j (desc, ncj>1).

__global__ __launch_bounds__(256, 3)
void fa_fwd(const float* __restrict__ Q, const float* __restrict__ K,
            const float* __restrict__ V, float* __restrict__ O,
            void* __restrict__ ws, const int nitems_q, const int Lt,
            const int nslot, const int hshift) {
  __shared__ bf16 Ksh[2][KB * DH];   // [buf][k][d]  8KB each, row 128B
  __shared__ bf16 Vts[2][DH * KB];   // [buf][d][k]  8KB each, row 128B
  __shared__ int sh_item;

  // queue = this block's physical XCD (only when split across 8 queues)
  unsigned xcc = 0;
  if (hshift == 1) asm("s_getreg_b32 %0, hwreg(HW_REG_XCC_ID)" : "=s"(xcc));
  const int qown = (hshift == 1) ? (int)(xcc & 7) : 0;
  const int hpq  = 1 << hshift;          // heads per queue (2 or 16)
  const int nq   = 16 >> hshift;         // queues (8 or 1)

  bf16*  wsO = (bf16*)((char*)ws + 1024);
  float* wsM = (float*)((char*)ws + 1024 + (size_t)nslot * 16384);
  float* wsL = wsM + (size_t)nslot * 128;

  const int tid = threadIdx.x;
  const int w   = tid >> 6;
  const int l   = tid & 63;
  const int lc  = l & 31;
  const int hi  = l >> 5;

  // staging assignments (KB=64)
  const int kr = tid >> 2, kc = (tid & 3) * 16;  // K: row, 16-col group
  const int dg = tid & 7,  kp = tid >> 3;        // V: d-group(8), k-pair [0,32)

  int qoff = 0;   // 0 = own queue; 1..nq-1 = steal sweep (correctness guard)
  for (;;) {
    __syncthreads();   // prev item's LDS reads done; sh_item reusable
    if (tid == 0) sh_item = (int)atomicAdd((unsigned*)ws + (((qown + qoff) % nq) * 16), 1u);
    __syncthreads();
    int c = sh_item;
    if (c >= nitems_q) {        // this queue drained -> advance sweep
      if (++qoff >= nq) break;  // all queues drained
      continue;
    }
    const int qi = (qown + qoff) % nq;

    // ---- decode: head innermost; then chunk-index OUTER, j desc inner ----
    const int head = qi + (c & (hpq - 1)) * nq;
    int j = -1, ci = 0;
    {
      int cc = c >> hshift;
      for (int cic = 0; cic < 8 && j < 0; ++cic) {
        for (int jj = NJ - 1; jj >= 0; --jj) {
          const int ncj = (2 * jj + 2 + Lt - 1) / Lt;
          if (cic < ncj) {
            if (cc == 0) { j = jj; ci = cic; break; }
            --cc;
          }
        }
      }
    }
    const int ncj_cur = (2 * j + 2 + Lt - 1) / Lt;
    int slot = -1;
    if (ncj_cur > 1) {
      int sb = 0;
      for (int jj = NJ - 1; jj > j; --jj) {
        const int ncj = (2 * jj + 2 + Lt - 1) / Lt;
        if (ncj > 1) sb += ncj;
      }
      slot = (sb + ci) * NH + head;
    }
    const int qb = j * QB;
    const int t0 = ci * Lt;
    const int t1 = min((ci + 1) * Lt, 2 * j + 2);

    const int qw = qb + w * WQ;
    const int qv = qw + lc;
    const float* Qh = Q + (size_t)head * SEQ * DH;
    const float* Kh = K + (size_t)head * SEQ * DH;
    const float* Vh = V + (size_t)head * SEQ * DH;

    // ---- Q as B-fragments (scale folds 1/8 and log2e) ----
    bf16x8 qf[4];
    {
      const float* qp = Qh + (size_t)qv * DH + hi * 8;
      const float sc = 0.125f * LOG2E;
#pragma unroll
      for (int ch = 0; ch < 4; ++ch) {
        float4 x = *(const float4*)(qp + ch * 16);
        float4 y = *(const float4*)(qp + ch * 16 + 4);
        bf16x8 f;
        f[0]=(bf16)(x.x*sc); f[1]=(bf16)(x.y*sc); f[2]=(bf16)(x.z*sc); f[3]=(bf16)(x.w*sc);
        f[4]=(bf16)(y.x*sc); f[5]=(bf16)(y.y*sc); f[6]=(bf16)(y.z*sc); f[7]=(bf16)(y.w*sc);
        qf[ch] = f;
      }
    }

    f32x16 o0 = {}, o1 = {};
    float m = -INFINITY, ls = 0.f;

    float4 kreg[4], vreg[4];
    // ---- load first tile into regs ----
    {
      const int kb0 = t0 * KB;
      const float* p = Kh + (size_t)(kb0 + kr) * DH + kc;
#pragma unroll
      for (int i = 0; i < 4; ++i) kreg[i] = ((const float4*)p)[i];
      const float* pv = Vh + (size_t)(kb0 + 2 * kp) * DH + dg * 8;
      vreg[0] = ((const float4*)pv)[0];
      vreg[1] = ((const float4*)pv)[1];
      vreg[2] = ((const float4*)(pv + DH))[0];
      vreg[3] = ((const float4*)(pv + DH))[1];
    }

    for (int t = t0; t < t1; ++t) {
      const int kb = t * KB;
      const int b  = (t - t0) & 1;

      // ---- write regs -> LDS[b] (swizzled) ----
      {
        const int Sk = (((kr & 7) ^ ((kr >> 3) & 7)) << 4);
#pragma unroll
        for (int q = 0; q < 2; ++q)
          *(bf16x8*)((char*)Ksh[b] + kr * 128 + ((kc * 2 + q * 16) ^ Sk)) =
              cvt8(kreg[2*q], kreg[2*q+1]);
        const int xbase = (kp * 4) ^ (dg << 4);
#pragma unroll
        for (int i = 0; i < 8; ++i) {
          const float lo = vreg[(i >> 2)    ][i & 3];
          const float hv = vreg[(i >> 2) + 2][i & 3];
          *(unsigned*)((char*)Vts[b] + (dg * 8 + i) * 128 + (xbase ^ (i << 4))) =
              pk(lo, hv);
        }
      }
      __syncthreads();   // single barrier per iter (dbuf covers the rest)

      // ---- issue next tile's loads early (hidden under compute) ----
      if (t + 1 < t1) {
        const int kn = kb + KB;
        const float* p = Kh + (size_t)(kn + kr) * DH + kc;
#pragma unroll
        for (int i = 0; i < 4; ++i) kreg[i] = ((const float4*)p)[i];
        const float* pv = Vh + (size_t)(kn + 2 * kp) * DH + dg * 8;
        vreg[0] = ((const float4*)pv)[0];
        vreg[1] = ((const float4*)pv)[1];
        vreg[2] = ((const float4*)(pv + DH))[0];
        vreg[3] = ((const float4*)(pv + DH))[1];
      }

      if (kb > qw + 31) continue;   // wave fully masked (barrier already done)

      // ---- S^T = K*Q on LDS[b] ----
      f32x16 st0 = {}, st1 = {};
#pragma unroll
      for (int kt = 0; kt < 2; ++kt) {
        const int row = kt * 32 + lc;
        const int Sr  = (((lc & 7) ^ ((kt * 4 + (lc >> 3)) & 7)) << 4);
        f32x16& st = kt ? st1 : st0;
#pragma unroll
        for (int ch = 0; ch < 4; ++ch) {
          const bf16x8 kf = *(const bf16x8*)((const char*)Ksh[b] +
              row * 128 + ((ch * 32 + hi * 16) ^ Sr));
          mfma32(st, kf, qf[ch]);
        }
      }

      if (kb + 63 > qw) {   // causal mask near diagonal
#pragma unroll
        for (int r = 0; r < 16; ++r) {
          const int kg = kb + ((r & 3) + 8 * (r >> 2) + 4 * hi);
          if (kg > qv)      st0[r] = -INFINITY;
          if (kg + 32 > qv) st1[r] = -INFINITY;
        }
      }

      // row max
      float acc[8];
#pragma unroll
      for (int i = 0; i < 8; ++i)
        acc[i] = fmaxf(fmaxf(st0[i], st0[i + 8]), fmaxf(st1[i], st1[i + 8]));
      acc[0]=fmaxf(acc[0],acc[4]); acc[1]=fmaxf(acc[1],acc[5]);
      acc[2]=fmaxf(acc[2],acc[6]); acc[3]=fmaxf(acc[3],acc[7]);
      acc[0]=fmaxf(acc[0],acc[2]); acc[1]=fmaxf(acc[1],acc[3]);
      float mx = fmaxf(acc[0], acc[1]);
      mx = fmaxf(mx, __shfl_xor(mx, 32));

      // defer-max rescale
      if (__any(mx > m + 8.0f)) {
        const float mn = fmaxf(m, mx);
        const float al = exp2a(m - mn);
        m = mn;
        ls *= al;
#pragma unroll
        for (int r = 0; r < 16; ++r) {
          const float aq = __shfl(al, (r & 3) + 8 * (r >> 2) + 4 * hi);
          o0[r] *= aq; o1[r] *= aq;
        }
      }

      // P = exp2(S-m), pack -> A-frag, consume in PV
      float rs = 0.f;
      const int S0 = (((lc & 7) ^ ((lc >> 3) & 7)) << 4);
      const int S1 = (((lc & 7) ^ (((lc >> 3) + 4) & 7)) << 4);
#pragma unroll
      for (int ks = 0; ks < 4; ++ks) {
        const f32x16& st = (ks < 2) ? st0 : st1;
        float p[8];
#pragma unroll
        for (int jj = 0; jj < 8; ++jj) p[jj] = exp2a(st[(ks & 1) * 8 + jj] - m);
        rs += ((p[0]+p[1])+(p[2]+p[3])) + ((p[4]+p[5])+(p[6]+p[7]));
        unsigned u0 = pk(p[0],p[1]), u1 = pk(p[2],p[3]);
        unsigned u2 = pk(p[4],p[5]), u3 = pk(p[6],p[7]);
        swap32(u0, u2); swap32(u1, u3);
        AFrag af; af.u[0]=u0; af.u[1]=u1; af.u[2]=u2; af.u[3]=u3;
        const int koff = ks * 32 + hi * 16;
        bf16x8 v0 = *(const bf16x8*)((const char*)Vts[b] + lc * 128 + (koff ^ S0));
        bf16x8 v1 = *(const bf16x8*)((const char*)Vts[b] + (lc + 32) * 128 + (koff ^ S1));
        mfma32(o0, af.v, v0);
        mfma32(o1, af.v, v1);
      }
      rs += __shfl_xor(rs, 32);
      ls += rs;
    }

    // ---- epilogue ----
    if (slot < 0) {
      const float inv = 1.0f / ls;
      float* Ob = O + (size_t)(head * SEQ + qw) * DH;
#pragma unroll
      for (int r = 0; r < 16; ++r) {
        const int row = (r & 3) + 8 * (r >> 2) + 4 * hi;
        const float iq = __shfl(inv, row);
        Ob[(size_t)row * DH + lc]      = o0[r] * iq;
        Ob[(size_t)row * DH + 32 + lc] = o1[r] * iq;
      }
    } else {
      bf16* po = wsO + (size_t)slot * (128 * 64);
#pragma unroll
      for (int r = 0; r < 16; ++r) {
        const int row = w * WQ + (r & 3) + 8 * (r >> 2) + 4 * hi;
        po[row * 64 + lc]      = (bf16)o0[r];
        po[row * 64 + 32 + lc] = (bf16)o1[r];
      }
      if (hi == 0) {
        wsM[slot * 128 + w * WQ + lc] = m;
        wsL[slot * 128 + w * WQ + lc] = ls;
      }
    }
  }
}

// merge nc partials per split q-block (exact online-softmax merge)
__global__ __launch_bounds__(256)
void fa_combine(float* __restrict__ O, const void* __restrict__ ws,
                const int Lt, const int nslot) {
  const bf16*  wsO = (const bf16*)((const char*)ws + 1024);
  const float* wsM = (const float*)((const char*)ws + 1024 + (size_t)nslot * 16384);
  const float* wsL = wsM + (size_t)nslot * 128;

  const int li = blockIdx.x * 256 + threadIdx.x;   // [0, 1024)
  const int dp = li & 7;
  const int r  = li >> 3;                          // [0, 128)
  const int sj = blockIdx.y;                       // split-j ordinal (desc)
  const int h  = blockIdx.z;

  // map sj -> (j, sbase, nc), same descending order as fa_fwd's slot layout
  int j = 0, sbase = 0, nc = 0;
  {
    int cnt = 0;
    for (int jj = NJ - 1; jj >= 0; --jj) {
      const int ncj = (2 * jj + 2 + Lt - 1) / Lt;
      if (ncj > 1) {
        if (cnt == sj) { j = jj; nc = ncj; break; }
        ++cnt; sbase += ncj;
      }
    }
  }

  float M = -INFINITY;
  for (int c = 0; c < nc; ++c)
    M = fmaxf(M, wsM[((sbase + c) * NH + h) * 128 + r]);

  float lt = 0.f, o[8] = {0.f,0.f,0.f,0.f,0.f,0.f,0.f,0.f};
  for (int c = 0; c < nc; ++c) {
    const int slot = (sbase + c) * NH + h;
    const float wgt = exp2f(wsM[slot * 128 + r] - M);
    lt += wgt * wsL[slot * 128 + r];
    const bf16x8 a = *(const bf16x8*)(wsO + (size_t)slot * 8192 + r * 64 + dp * 8);
#pragma unroll
    for (int jj = 0; jj < 8; ++jj) o[jj] += wgt * (float)a[jj];
  }
  const float inv = 1.0f / lt;

  float* out = O + ((size_t)h * SEQ + j * QB + r) * DH + dp * 8;
#pragma unroll
  for (int jj = 0; jj < 8; ++jj) out[jj] = o[jj] * inv;
}

extern "C" void kernel_launch(void* const* d_in, const int* in_sizes, int n_in,
                              void* d_out, int out_size, void* d_ws, size_t ws_size,
                              hipStream_t stream) {
  const float* q = (const float*)d_in[0];
  const float* k = (const float*)d_in[1];
  const float* v = (const float*)d_in[2];
  float* out = (float*)d_out;

  // pick finest chunk length that fits ws; 64 = monolithic fallback
  const int cand[5] = {8, 16, 22, 32, 64};
  int Lt = 64, nslot = 0, iph = 0, nsj = 0;
  for (int ic = 0; ic < 5; ++ic) {
    const int L = cand[ic];
    int sl = 0, it = 0, js = 0;
    for (int j = 0; j < NJ; ++j) {
      const int nc = (2 * j + 2 + L - 1) / L;
      it += nc;
      if (nc > 1) { sl += nc * NH; ++js; }
    }
    const size_t need = 1024 + (size_t)sl * (16384 + 512 + 512);
    if (need <= ws_size || L == 64) { Lt = L; nslot = sl; iph = it; nsj = js; break; }
  }
  const int hshift   = (Lt == 64) ? 4 : 1;       // heads/queue = 16 or 2
  const int nitems_q = (1 << hshift) * iph;

  zero_ctr<<<1, 64, 0, stream>>>((unsigned*)d_ws);
  fa_fwd<<<1024, 256, 0, stream>>>(q, k, v, out, d_ws, nitems_q, Lt, nslot, hshift);
  if (nsj > 0) fa_combine<<<dim3(4, nsj, NH), 256, 0, stream>>>(out, d_ws, Lt, nslot);
}